// Round 1
// baseline (803.733 us; speedup 1.0000x reference)
//
#include <hip/hip_runtime.h>
#include <math.h>

#define CONF_T 0.05f
#define NEGF  -1e10f
#define NCLS 16
#define TDET 100
#define CAP 4096
#define SLOTS 16   // CAP/256
#define MTOT (NCLS*TDET)  // 1600

// ---------------- Kernel 1: decode boxes + per-anchor class/score ----------------
__global__ __launch_bounds__(256) void k_decode(
    const float* __restrict__ pred, const float* __restrict__ anch,
    float* __restrict__ boxes, float* __restrict__ score, int* __restrict__ cls,
    int BN, int N)
{
  #pragma clang fp contract(off)
  int i = blockIdx.x * 256 + threadIdx.x;
  if (i >= BN) return;
  int n = i % N;
  const float* p = pred + (size_t)i * 20;
  float4 a = reinterpret_cast<const float4*>(anch)[n];  // cx, cy, w, h
  float xx = p[0] * a.z + a.x;
  float yy = p[1] * a.w + a.y;
  float wx = expf(p[2]) * a.z;
  float wy = expf(p[3]) * a.w;
  float hx = 0.5f * wx, hy = 0.5f * wy;
  float4 bx;
  bx.x = xx - hx; bx.y = yy - hy; bx.z = xx + hx; bx.w = yy + hy;
  reinterpret_cast<float4*>(boxes)[i] = bx;
  // argmax over sigmoids (compare sigmoid values, strict > keeps first index on ties)
  float best = -1.0f; int bi = 0;
  #pragma unroll
  for (int c = 0; c < NCLS; ++c) {
    float s = 1.0f / (1.0f + expf(-p[4 + c]));
    if (s > best) { best = s; bi = c; }
  }
  score[i] = best;
  cls[i] = (best >= CONF_T) ? bi : -1;
}

// ---------------- Kernel 2: per-(b,c) soft-NMS, one block per lane ----------------
__global__ __launch_bounds__(256) void k_nms(
    const float* __restrict__ boxes, const float* __restrict__ score,
    const int* __restrict__ cls,
    float* __restrict__ out_box, float* __restrict__ out_sc, int* __restrict__ out_pick,
    int N)
{
  #pragma clang fp contract(off)
  const int bc = blockIdx.x;
  const int b = bc >> 4, c = bc & 15;
  const int t = threadIdx.x;

  __shared__ int   s_idx[CAP];
  __shared__ float s_sc[CAP];
  __shared__ int   s_wtot[4];
  __shared__ float s_rs[4];
  __shared__ int   s_rj[4];
  __shared__ float s_bs;
  __shared__ int   s_bj;
  __shared__ float s_box[4];

  const int*   clsb = cls   + (size_t)b * N;
  const float* scb  = score + (size_t)b * N;

  // ---- stable compaction (ascending anchor index) into LDS ----
  int K = 0;
  for (int base = 0; base < N; base += 256) {
    int n = base + t;
    bool m = (n < N) && (clsb[n] == c);
    unsigned long long ball = __ballot(m);
    int lane = t & 63, w = t >> 6;
    if (lane == 0) s_wtot[w] = __popcll(ball);
    __syncthreads();
    int off = 0;
    #pragma unroll
    for (int i = 0; i < 4; ++i) if (i < w) off += s_wtot[i];
    int tot = s_wtot[0] + s_wtot[1] + s_wtot[2] + s_wtot[3];
    if (m) {
      int wpre = __popcll(ball & ((1ull << lane) - 1ull));
      int j = K + off + wpre;
      if (j < CAP) { s_idx[j] = n; s_sc[j] = scb[n]; }
    }
    K += tot;
    __syncthreads();
  }
  if (K > CAP) K = CAP;

  // ---- load candidates into registers: thread t owns j = t + 256*k ----
  float rsc[SLOTS];
  float rbx[SLOTS][4];
  #pragma unroll
  for (int k = 0; k < SLOTS; ++k) {
    int j = k * 256 + t;
    if (j < K) {
      rsc[k] = s_sc[j];
      const float* bp = boxes + ((size_t)b * N + s_idx[j]) * 4;
      rbx[k][0] = bp[0]; rbx[k][1] = bp[1]; rbx[k][2] = bp[2]; rbx[k][3] = bp[3];
    } else {
      rsc[k] = NEGF;
      rbx[k][0] = rbx[k][1] = rbx[k][2] = rbx[k][3] = 0.0f;
    }
  }

  float* ob  = out_box  + (size_t)bc * TDET * 4;
  float* osc = out_sc   + (size_t)bc * TDET;
  int*   opk = out_pick + (size_t)bc * TDET;

  int iter = 0;
  for (; iter < TDET; ++iter) {
    // local argmax (strict > => lowest slot k, i.e. lowest j, on ties)
    float bs = NEGF; int bj = 0x7fffffff;
    #pragma unroll
    for (int k = 0; k < SLOTS; ++k) {
      if (rsc[k] > bs) { bs = rsc[k]; bj = k * 256 + t; }
    }
    // wave reduce: max score, tie -> min j
    #pragma unroll
    for (int d = 1; d < 64; d <<= 1) {
      float os = __shfl_xor(bs, d);
      int   oj = __shfl_xor(bj, d);
      if (os > bs || (os == bs && oj < bj)) { bs = os; bj = oj; }
    }
    {
      int lane = t & 63, w = t >> 6;
      if (lane == 0) { s_rs[w] = bs; s_rj[w] = bj; }
    }
    __syncthreads();
    if (t == 0) {
      float B0 = s_rs[0]; int J0 = s_rj[0];
      for (int i = 1; i < 4; ++i) {
        if (s_rs[i] > B0 || (s_rs[i] == B0 && s_rj[i] < J0)) { B0 = s_rs[i]; J0 = s_rj[i]; }
      }
      s_bs = B0; s_bj = J0;
    }
    __syncthreads();
    float bestS = s_bs; int bestJ = s_bj;
    if (bestS < CONF_T) break;   // uniform: no further picks possible

    // owner publishes selected box (static register indexing)
    if ((bestJ & 255) == t) {
      #pragma unroll
      for (int k = 0; k < SLOTS; ++k) {
        if (k == (bestJ >> 8)) {
          s_box[0] = rbx[k][0]; s_box[1] = rbx[k][1];
          s_box[2] = rbx[k][2]; s_box[3] = rbx[k][3];
        }
      }
    }
    __syncthreads();
    float sx1 = s_box[0], sy1 = s_box[1], sx2 = s_box[2], sy2 = s_box[3];
    if (t == 0) {
      ob[iter * 4 + 0] = sx1; ob[iter * 4 + 1] = sy1;
      ob[iter * 4 + 2] = sx2; ob[iter * 4 + 3] = sy2;
      osc[iter] = bestS; opk[iter] = 1;
    }
    float areaS = (sx2 - sx1) * (sy2 - sy1);
    #pragma unroll
    for (int k = 0; k < SLOTS; ++k) {
      int j = k * 256 + t;
      if (j >= K) continue;
      if (j == bestJ) { rsc[k] = NEGF; continue; }
      float ltx = fmaxf(sx1, rbx[k][0]);
      float lty = fmaxf(sy1, rbx[k][1]);
      float rbv = fminf(sx2, rbx[k][2]);
      float rby = fminf(sy2, rbx[k][3]);
      float wx = fmaxf(rbv - ltx, 0.0f);
      float wy = fmaxf(rby - lty, 0.0f);
      float inter = wx * wy;
      float areaB = (rbx[k][2] - rbx[k][0]) * (rbx[k][3] - rbx[k][1]);
      float uni = (areaS + areaB) - inter;
      float iou = (uni > 0.0f) ? (inter / uni) : 0.0f;
      if (iou > 0.5f) rsc[k] = NEGF;
      else            rsc[k] = rsc[k] * expf((-10.0f * iou) * iou);
    }
    // no sync needed here: s_rs/s_box rewrites next iter are barrier-protected
  }
  // remaining steps have pick=false
  for (int r = iter + t; r < TDET; r += 256) opk[r] = 0;
}

// ---------------- Kernel 3: per-batch compaction + top-100 + output ----------------
__global__ __launch_bounds__(256) void k_post(
    const float* __restrict__ out_box, const float* __restrict__ out_sc,
    const int* __restrict__ out_pick,
    float* __restrict__ out, int B)
{
  #pragma clang fp contract(off)
  const int b = blockIdx.x;
  const int t = threadIdx.x;

  __shared__ float p_sc[MTOT];
  __shared__ float p_bx[MTOT * 4];
  __shared__ unsigned char p_v[MTOT];
  __shared__ float q_sc[MTOT];
  __shared__ short q_m[MTOT];
  __shared__ int   s_wtot[4];
  __shared__ float o_sc[TDET];
  __shared__ float o_cl[TDET];
  __shared__ float o_bx[TDET * 4];

  // load class-major entries (m = c*100 + step)
  for (int m = t; m < MTOT; m += 256) {
    int c = m / TDET, tt = m % TDET;
    int lane = b * NCLS + c;
    int pk = out_pick[(size_t)lane * TDET + tt];
    p_v[m] = (unsigned char)pk;
    if (pk) {
      p_sc[m] = out_sc[(size_t)lane * TDET + tt];
      p_bx[m * 4 + 0] = out_box[((size_t)lane * TDET + tt) * 4 + 0];
      p_bx[m * 4 + 1] = out_box[((size_t)lane * TDET + tt) * 4 + 1];
      p_bx[m * 4 + 2] = out_box[((size_t)lane * TDET + tt) * 4 + 2];
      p_bx[m * 4 + 3] = out_box[((size_t)lane * TDET + tt) * 4 + 3];
    } else {
      p_sc[m] = 0.0f;
      p_bx[m * 4 + 0] = 0.0f; p_bx[m * 4 + 1] = 0.0f;
      p_bx[m * 4 + 2] = 0.0f; p_bx[m * 4 + 3] = 0.0f;
    }
  }
  __syncthreads();

  // stable compaction of valid entries (class-major order preserved)
  int running = 0;
  for (int base = 0; base < MTOT; base += 256) {
    int m = base + t;
    bool v = (m < MTOT) && p_v[m];
    unsigned long long ball = __ballot(v);
    int lane = t & 63, w = t >> 6;
    if (lane == 0) s_wtot[w] = __popcll(ball);
    __syncthreads();
    int off = 0;
    #pragma unroll
    for (int i = 0; i < 4; ++i) if (i < w) off += s_wtot[i];
    int tot = s_wtot[0] + s_wtot[1] + s_wtot[2] + s_wtot[3];
    if (v) {
      int wpre = __popcll(ball & ((1ull << lane) - 1ull));
      int j = running + off + wpre;
      q_sc[j] = p_sc[m];
      q_m[j] = (short)m;
    }
    running += tot;
    __syncthreads();
  }
  int nv = running;
  bool over = nv > TDET;

  // init output staging with pad defaults
  if (t < TDET) {
    o_sc[t] = 0.0f; o_cl[t] = -1.0f;
    o_bx[t * 4 + 0] = 0.0f; o_bx[t * 4 + 1] = 0.0f;
    o_bx[t * 4 + 2] = 0.0f; o_bx[t * 4 + 3] = 0.0f;
  }
  __syncthreads();

  // rank and scatter (stable: ties by compacted position)
  for (int k = 0; k < 7; ++k) {
    int p = t + k * 256;
    if (p >= nv) break;
    int r;
    if (!over) {
      r = p;
    } else {
      r = 0;
      float sp = q_sc[p];
      for (int j = 0; j < nv; ++j) {
        float sj = q_sc[j];
        if (sj > sp || (sj == sp && j < p)) r++;
      }
    }
    if (r < TDET) {
      int m = q_m[p];
      o_sc[r] = q_sc[p];
      o_cl[r] = (float)(m / TDET);
      o_bx[r * 4 + 0] = p_bx[m * 4 + 0];
      o_bx[r * 4 + 1] = p_bx[m * 4 + 1];
      o_bx[r * 4 + 2] = p_bx[m * 4 + 2];
      o_bx[r * 4 + 3] = p_bx[m * 4 + 3];
    }
  }
  __syncthreads();

  // write: [B] valid, [B,100,4] boxes, [B,100] scores, [B,100] classes (all f32)
  int base_box = B;
  int base_sc  = B + B * TDET * 4;
  int base_cl  = B + B * TDET * 4 + B * TDET;
  if (t == 0) out[b] = (float)(nv < TDET ? nv : TDET);
  if (t < TDET) {
    int o = b * TDET + t;
    out[base_box + o * 4 + 0] = o_bx[t * 4 + 0];
    out[base_box + o * 4 + 1] = o_bx[t * 4 + 1];
    out[base_box + o * 4 + 2] = o_bx[t * 4 + 2];
    out[base_box + o * 4 + 3] = o_bx[t * 4 + 3];
    out[base_sc + o] = o_sc[t];
    out[base_cl + o] = o_cl[t];
  }
}

extern "C" void kernel_launch(void* const* d_in, const int* in_sizes, int n_in,
                              void* d_out, int out_size, void* d_ws, size_t ws_size,
                              hipStream_t stream) {
  const float* pred = (const float*)d_in[0];
  const float* anch = (const float*)d_in[1];
  int N  = in_sizes[1] / 4;       // 49104
  int BN = in_sizes[0] / 20;      // B*N
  int B  = BN / N;                // 4

  char* ws = (char*)d_ws;
  size_t off = 0;
  float* boxes = (float*)(ws + off); off += (size_t)BN * 4 * sizeof(float);
  float* score = (float*)(ws + off); off += (size_t)BN * sizeof(float);
  int*   cls   = (int*)(ws + off);   off += (size_t)BN * sizeof(int);
  float* obox  = (float*)(ws + off); off += (size_t)B * NCLS * TDET * 4 * sizeof(float);
  float* osc   = (float*)(ws + off); off += (size_t)B * NCLS * TDET * sizeof(float);
  int*   opick = (int*)(ws + off);   off += (size_t)B * NCLS * TDET * sizeof(int);

  k_decode<<<(BN + 255) / 256, 256, 0, stream>>>(pred, anch, boxes, score, cls, BN, N);
  k_nms<<<B * NCLS, 256, 0, stream>>>(boxes, score, cls, obox, osc, opick, N);
  k_post<<<B, 256, 0, stream>>>(obox, osc, opick, (float*)d_out, B);
}

// Round 2
// 348.555 us; speedup vs baseline: 2.3059x; 2.3059x over previous
//
#include <hip/hip_runtime.h>
#include <math.h>

#define CONF_T 0.05f
#define NEGF  -1e10f
#define NCLS 16
#define TDET 100
#define CAP 4096
#define MTOT (NCLS*TDET)  // 1600

// pack (score, j) -> u64 so that umax == (max score, tie -> min j)
__device__ __forceinline__ unsigned long long packkey(float s, int j) {
  unsigned int b = __float_as_uint(s);
  b = (b & 0x80000000u) ? ~b : (b | 0x80000000u);   // total order for floats
  return ((unsigned long long)b << 32) | (unsigned int)(~j);
}
__device__ __forceinline__ float unpack_score(unsigned long long k) {
  unsigned int h = (unsigned int)(k >> 32);
  unsigned int b = (h & 0x80000000u) ? (h & 0x7fffffffu) : ~h;
  return __uint_as_float(b);
}

// ---------------- K1: decode boxes + class/score + per-chunk class counts ----------------
__global__ __launch_bounds__(256) void k_decode(
    const float* __restrict__ pred, const float* __restrict__ anch,
    float* __restrict__ boxes, float* __restrict__ score, int* __restrict__ cls,
    int* __restrict__ counts, int N, int nchunk)
{
  #pragma clang fp contract(off)
  const int b = blockIdx.x / nchunk;
  const int chunk = blockIdx.x % nchunk;
  const int t = threadIdx.x;
  const int n = chunk * 256 + t;

  __shared__ int hist[NCLS];
  if (t < NCLS) hist[t] = 0;
  __syncthreads();

  int v = -1;
  if (n < N) {
    const size_t i = (size_t)b * N + n;
    const float4* p4 = reinterpret_cast<const float4*>(pred + i * 20);
    float4 v0 = p4[0], v1 = p4[1], v2 = p4[2], v3 = p4[3], v4 = p4[4];
    float4 a = reinterpret_cast<const float4*>(anch)[n];  // cx, cy, w, h
    float xx = v0.x * a.z + a.x;
    float yy = v0.y * a.w + a.y;
    float wx = expf(v0.z) * a.z;
    float wy = expf(v0.w) * a.w;
    float hx = 0.5f * wx, hy = 0.5f * wy;
    float4 bx;
    bx.x = xx - hx; bx.y = yy - hy; bx.z = xx + hx; bx.w = yy + hy;
    reinterpret_cast<float4*>(boxes)[i] = bx;

    float lg[NCLS] = {v1.x, v1.y, v1.z, v1.w, v2.x, v2.y, v2.z, v2.w,
                      v3.x, v3.y, v3.z, v3.w, v4.x, v4.y, v4.z, v4.w};
    float best = -1.0f; int bi = 0;
    #pragma unroll
    for (int c = 0; c < NCLS; ++c) {
      float s = 1.0f / (1.0f + expf(-lg[c]));
      if (s > best) { best = s; bi = c; }
    }
    score[i] = best;
    v = (best >= CONF_T) ? bi : -1;
    cls[i] = v;
  }

  int lane = t & 63;
  #pragma unroll
  for (int c = 0; c < NCLS; ++c) {
    unsigned long long bl = __ballot(v == c);
    if (lane == 0 && bl) atomicAdd(&hist[c], __popcll(bl));
  }
  __syncthreads();
  if (t < NCLS) counts[(b * NCLS + t) * nchunk + chunk] = hist[t];
}

// ---------------- K2: per-(b,c) exclusive scan over chunk counts ----------------
__global__ __launch_bounds__(256) void k_scan(
    const int* __restrict__ counts, int* __restrict__ offs, int* __restrict__ ktot,
    int nchunk)
{
  const int bc = blockIdx.x;
  const int t = threadIdx.x;
  __shared__ int c_[256];
  __shared__ int o_[257];
  if (t < nchunk) c_[t] = counts[bc * nchunk + t];
  __syncthreads();
  if (t == 0) {
    int run = 0;
    for (int i = 0; i < nchunk; ++i) { o_[i] = run; run += c_[i]; }
    o_[nchunk] = run;
  }
  __syncthreads();
  if (t < nchunk) offs[bc * nchunk + t] = o_[t];
  if (t == 0) ktot[bc] = o_[nchunk];
}

// ---------------- K3: stable parallel scatter into per-(b,c) candidate lists ----------------
__global__ __launch_bounds__(256) void k_scatter(
    const float* __restrict__ score, const int* __restrict__ cls,
    const float* __restrict__ boxes, const int* __restrict__ offs,
    float* __restrict__ cand_sc, float* __restrict__ cand_bx,
    int N, int nchunk)
{
  const int b = blockIdx.x / nchunk;
  const int chunk = blockIdx.x % nchunk;
  const int t = threadIdx.x;
  const int n = chunk * 256 + t;

  __shared__ int wcnt[4][NCLS];
  int v = (n < N) ? cls[(size_t)b * N + n] : -1;
  int lane = t & 63, w = t >> 6;
  int myrank = 0;
  #pragma unroll
  for (int c = 0; c < NCLS; ++c) {
    unsigned long long bl = __ballot(v == c);
    if (lane == 0) wcnt[w][c] = __popcll(bl);
    if (v == c) myrank = __popcll(bl & ((1ull << lane) - 1ull));
  }
  __syncthreads();
  if (v >= 0) {
    int pre = 0;
    #pragma unroll
    for (int i = 0; i < 4; ++i) if (i < w) pre += wcnt[i][v];
    int pos = offs[(b * NCLS + v) * nchunk + chunk] + pre + myrank;
    if (pos < CAP) {
      int bc = b * NCLS + v;
      cand_sc[(size_t)bc * CAP + pos] = score[(size_t)b * N + n];
      reinterpret_cast<float4*>(cand_bx)[(size_t)bc * CAP + pos] =
          reinterpret_cast<const float4*>(boxes)[(size_t)b * N + n];
    }
  }
}

// ---------------- K4: per-(b,c) soft-NMS, 1024 threads, 2 barriers/iter ----------------
__global__ __launch_bounds__(1024) void k_nms(
    const float* __restrict__ cand_sc, const float* __restrict__ cand_bx,
    const int* __restrict__ ktot,
    float* __restrict__ out_box, float* __restrict__ out_sc, int* __restrict__ out_pick)
{
  #pragma clang fp contract(off)
  const int bc = blockIdx.x;
  const int t = threadIdx.x;
  const int lane = t & 63, w = t >> 6;

  __shared__ unsigned long long s_key[16];
  __shared__ float s_wbox[16][4];

  int K = ktot[bc]; if (K > CAP) K = CAP;

  float rsc[4];
  float rbx[4][4];
  #pragma unroll
  for (int k = 0; k < 4; ++k) {
    int j = k * 1024 + t;
    if (j < K) {
      rsc[k] = cand_sc[(size_t)bc * CAP + j];
      float4 bb = reinterpret_cast<const float4*>(cand_bx)[(size_t)bc * CAP + j];
      rbx[k][0] = bb.x; rbx[k][1] = bb.y; rbx[k][2] = bb.z; rbx[k][3] = bb.w;
    } else {
      rsc[k] = NEGF;
      rbx[k][0] = rbx[k][1] = rbx[k][2] = rbx[k][3] = 0.0f;
    }
  }

  float* ob  = out_box  + (size_t)bc * TDET * 4;
  float* osc = out_sc   + (size_t)bc * TDET;
  int*   opk = out_pick + (size_t)bc * TDET;

  int iter = 0;
  for (; iter < TDET; ++iter) {
    // local argmax over live slots (strict > => lowest slot/j on ties)
    float bs = NEGF; int bk = 0;
    #pragma unroll
    for (int k = 0; k < 4; ++k) {
      if (rsc[k] > bs) { bs = rsc[k]; bk = k; }
    }
    unsigned long long key = packkey(bs, bk * 1024 + t);
    #pragma unroll
    for (int d = 1; d < 64; d <<= 1) {
      unsigned long long o = __shfl_xor(key, d);
      if (o > key) key = o;
    }
    if (lane == 0) s_key[w] = key;
    // wave-best owner publishes its box before the barrier
    int wj = (int)(~(unsigned int)key);
    if ((wj & 1023) == t) {
      int sk = (wj >> 10) & 3;
      #pragma unroll
      for (int k = 0; k < 4; ++k)
        if (k == sk) {
          s_wbox[w][0] = rbx[k][0]; s_wbox[w][1] = rbx[k][1];
          s_wbox[w][2] = rbx[k][2]; s_wbox[w][3] = rbx[k][3];
        }
    }
    __syncthreads();

    unsigned long long bkey = s_key[0];
    #pragma unroll
    for (int i = 1; i < 16; ++i) {
      unsigned long long o = s_key[i];
      if (o > bkey) bkey = o;
    }
    float bestS = unpack_score(bkey);
    if (bestS < CONF_T) break;   // uniform: no further picks possible

    int bestJ = (int)(~(unsigned int)bkey);
    int ww = (bestJ & 1023) >> 6;
    float sx1 = s_wbox[ww][0], sy1 = s_wbox[ww][1];
    float sx2 = s_wbox[ww][2], sy2 = s_wbox[ww][3];
    if (t == 0) {
      ob[iter * 4 + 0] = sx1; ob[iter * 4 + 1] = sy1;
      ob[iter * 4 + 2] = sx2; ob[iter * 4 + 3] = sy2;
      osc[iter] = bestS; opk[iter] = 1;
    }
    float areaS = (sx2 - sx1) * (sy2 - sy1);
    #pragma unroll
    for (int k = 0; k < 4; ++k) {
      int j = k * 1024 + t;
      if (j >= K) continue;
      if (rsc[k] == NEGF) continue;      // dead: can never be picked again
      if (j == bestJ) { rsc[k] = NEGF; continue; }
      float ltx = fmaxf(sx1, rbx[k][0]);
      float lty = fmaxf(sy1, rbx[k][1]);
      float rbv = fminf(sx2, rbx[k][2]);
      float rby = fminf(sy2, rbx[k][3]);
      float wx = fmaxf(rbv - ltx, 0.0f);
      float wy = fmaxf(rby - lty, 0.0f);
      float inter = wx * wy;
      float areaB = (rbx[k][2] - rbx[k][0]) * (rbx[k][3] - rbx[k][1]);
      float uni = (areaS + areaB) - inter;
      float iou = (uni > 0.0f) ? (inter / uni) : 0.0f;
      float ns;
      if (iou > 0.5f) ns = NEGF;
      else {
        ns = rsc[k] * expf((-10.0f * iou) * iou);
        if (ns < CONF_T) ns = NEGF;      // pruning: output-equivalent
      }
      rsc[k] = ns;
    }
    __syncthreads();
  }
  for (int r = iter + t; r < TDET; r += 1024) opk[r] = 0;
}

// ---------------- K5: per-batch compaction + stable top-100 (bitonic) ----------------
__global__ __launch_bounds__(1024) void k_post(
    const float* __restrict__ out_box, const float* __restrict__ out_sc,
    const int* __restrict__ out_pick,
    float* __restrict__ out, int B)
{
  #pragma clang fp contract(off)
  const int b = blockIdx.x;
  const int t = threadIdx.x;

  __shared__ float p_sc[MTOT];
  __shared__ float p_bx[MTOT * 4];
  __shared__ unsigned char p_v[MTOT];
  __shared__ float q_sc[MTOT];
  __shared__ short q_m[MTOT];
  __shared__ int s_wtot[16];
  __shared__ unsigned long long s_key[2048];

  // load class-major entries (m = c*100 + step)
  for (int m = t; m < MTOT; m += 1024) {
    int c = m / TDET, tt = m % TDET;
    int lanebc = b * NCLS + c;
    int pk = out_pick[(size_t)lanebc * TDET + tt];
    p_v[m] = (unsigned char)pk;
    if (pk) {
      p_sc[m] = out_sc[(size_t)lanebc * TDET + tt];
      p_bx[m * 4 + 0] = out_box[((size_t)lanebc * TDET + tt) * 4 + 0];
      p_bx[m * 4 + 1] = out_box[((size_t)lanebc * TDET + tt) * 4 + 1];
      p_bx[m * 4 + 2] = out_box[((size_t)lanebc * TDET + tt) * 4 + 2];
      p_bx[m * 4 + 3] = out_box[((size_t)lanebc * TDET + tt) * 4 + 3];
    } else {
      p_sc[m] = 0.0f;
      p_bx[m * 4 + 0] = 0.0f; p_bx[m * 4 + 1] = 0.0f;
      p_bx[m * 4 + 2] = 0.0f; p_bx[m * 4 + 3] = 0.0f;
    }
  }
  __syncthreads();

  // stable compaction (class-major order preserved)
  int running = 0;
  for (int base = 0; base < MTOT; base += 1024) {
    int m = base + t;
    bool v = (m < MTOT) && p_v[m];
    unsigned long long ball = __ballot(v);
    int lane = t & 63, w = t >> 6;
    if (lane == 0) s_wtot[w] = __popcll(ball);
    __syncthreads();
    int off = 0, tot = 0;
    #pragma unroll
    for (int i = 0; i < 16; ++i) {
      int ci = s_wtot[i];
      if (i < w) off += ci;
      tot += ci;
    }
    if (v) {
      int wpre = __popcll(ball & ((1ull << lane) - 1ull));
      int j = running + off + wpre;
      q_sc[j] = p_sc[m];
      q_m[j] = (short)m;
    }
    running += tot;
    __syncthreads();
  }
  int nv = running;
  bool over = nv > TDET;

  if (over) {
    // keys: inverted so ascending bitonic == (score desc, position asc)
    for (int e = t; e < 2048; e += 1024) {
      unsigned long long kk = 0;
      if (e < nv) {
        unsigned int sb = __float_as_uint(q_sc[e]);   // valid scores > 0
        kk = ((unsigned long long)sb << 32) | (unsigned int)(~e);
      }
      s_key[e] = ~kk;
    }
    for (int kk2 = 2; kk2 <= 2048; kk2 <<= 1) {
      for (int j = kk2 >> 1; j > 0; j >>= 1) {
        __syncthreads();
        int e = ((t & ~(j - 1)) << 1) | (t & (j - 1));
        int q = e | j;
        unsigned long long a = s_key[e], bb = s_key[q];
        bool up = ((e & kk2) == 0);
        bool sw = up ? (a > bb) : (a < bb);
        if (sw) { s_key[e] = bb; s_key[q] = a; }
      }
    }
    __syncthreads();
  }

  // write: [B] valid, [B,100,4] boxes, [B,100] scores, [B,100] classes (all f32)
  int vd = nv < TDET ? nv : TDET;
  int base_box = B;
  int base_sc  = B + B * TDET * 4;
  int base_cl  = base_sc + B * TDET;
  if (t == 0) out[b] = (float)vd;
  if (t < TDET) {
    float sc = 0.0f, cl = -1.0f, b0 = 0.0f, b1 = 0.0f, b2 = 0.0f, b3 = 0.0f;
    int p = -1;
    if (t < nv) p = over ? (int)(unsigned int)s_key[t] : t;
    if (p >= 0) {
      int m = q_m[p];
      sc = q_sc[p];
      cl = (float)(m / TDET);
      b0 = p_bx[m * 4 + 0]; b1 = p_bx[m * 4 + 1];
      b2 = p_bx[m * 4 + 2]; b3 = p_bx[m * 4 + 3];
    }
    int o = b * TDET + t;
    out[base_box + o * 4 + 0] = b0;
    out[base_box + o * 4 + 1] = b1;
    out[base_box + o * 4 + 2] = b2;
    out[base_box + o * 4 + 3] = b3;
    out[base_sc + o] = sc;
    out[base_cl + o] = cl;
  }
}

extern "C" void kernel_launch(void* const* d_in, const int* in_sizes, int n_in,
                              void* d_out, int out_size, void* d_ws, size_t ws_size,
                              hipStream_t stream) {
  const float* pred = (const float*)d_in[0];
  const float* anch = (const float*)d_in[1];
  int N  = in_sizes[1] / 4;       // 49104
  int BN = in_sizes[0] / 20;      // B*N
  int B  = BN / N;                // 4
  int nchunk = (N + 255) / 256;   // 192
  int NBC = B * NCLS;             // 64

  char* ws = (char*)d_ws;
  size_t off = 0;
  float* boxes  = (float*)(ws + off); off += (size_t)BN * 4 * sizeof(float);
  float* candbx = (float*)(ws + off); off += (size_t)NBC * CAP * 4 * sizeof(float);
  float* obox   = (float*)(ws + off); off += (size_t)NBC * TDET * 4 * sizeof(float);
  float* score  = (float*)(ws + off); off += (size_t)BN * sizeof(float);
  float* candsc = (float*)(ws + off); off += (size_t)NBC * CAP * sizeof(float);
  float* osc    = (float*)(ws + off); off += (size_t)NBC * TDET * sizeof(float);
  int*   cls    = (int*)(ws + off);   off += (size_t)BN * sizeof(int);
  int*   counts = (int*)(ws + off);   off += (size_t)NBC * nchunk * sizeof(int);
  int*   offs   = (int*)(ws + off);   off += (size_t)NBC * nchunk * sizeof(int);
  int*   ktot   = (int*)(ws + off);   off += (size_t)NBC * sizeof(int);
  int*   opick  = (int*)(ws + off);   off += (size_t)NBC * TDET * sizeof(int);

  k_decode<<<B * nchunk, 256, 0, stream>>>(pred, anch, boxes, score, cls, counts, N, nchunk);
  k_scan<<<NBC, 256, 0, stream>>>(counts, offs, ktot, nchunk);
  k_scatter<<<B * nchunk, 256, 0, stream>>>(score, cls, boxes, offs, candsc, candbx, N, nchunk);
  k_nms<<<NBC, 1024, 0, stream>>>(candsc, candbx, ktot, obox, osc, opick);
  k_post<<<B, 1024, 0, stream>>>(obox, osc, opick, (float*)d_out, B);
}

// Round 3
// 252.465 us; speedup vs baseline: 3.1835x; 1.3806x over previous
//
#include <hip/hip_runtime.h>
#include <math.h>

#define CONF_T 0.05f
#define NEGF  -1e10f
#define NCLS 16
#define TDET 100
#define CAP 4096
#define MTOT (NCLS*TDET)  // 1600

// pack (score, j) -> u64 so that umax == (max score, tie -> min j)
__device__ __forceinline__ unsigned long long packkey(float s, int j) {
  unsigned int b = __float_as_uint(s);
  b = (b & 0x80000000u) ? ~b : (b | 0x80000000u);   // total order for floats
  return ((unsigned long long)b << 32) | (unsigned int)(~j);
}
__device__ __forceinline__ float unpack_score(unsigned long long k) {
  unsigned int h = (unsigned int)(k >> 32);
  unsigned int b = (h & 0x80000000u) ? (h & 0x7fffffffu) : ~h;
  return __uint_as_float(b);
}

// ---------------- K1: decode boxes + class/score + per-chunk class counts ----------------
__global__ __launch_bounds__(256) void k_decode(
    const float* __restrict__ pred, const float* __restrict__ anch,
    float* __restrict__ boxes, float* __restrict__ score, int* __restrict__ cls,
    int* __restrict__ counts, int N, int nchunk)
{
  #pragma clang fp contract(off)
  const int b = blockIdx.x / nchunk;
  const int chunk = blockIdx.x % nchunk;
  const int t = threadIdx.x;
  const int n = chunk * 256 + t;

  __shared__ int hist[NCLS];
  if (t < NCLS) hist[t] = 0;
  __syncthreads();

  int v = -1;
  if (n < N) {
    const size_t i = (size_t)b * N + n;
    const float4* p4 = reinterpret_cast<const float4*>(pred + i * 20);
    float4 v0 = p4[0], v1 = p4[1], v2 = p4[2], v3 = p4[3], v4 = p4[4];
    float4 a = reinterpret_cast<const float4*>(anch)[n];  // cx, cy, w, h
    float xx = v0.x * a.z + a.x;
    float yy = v0.y * a.w + a.y;
    float wx = expf(v0.z) * a.z;
    float wy = expf(v0.w) * a.w;
    float hx = 0.5f * wx, hy = 0.5f * wy;
    float4 bx;
    bx.x = xx - hx; bx.y = yy - hy; bx.z = xx + hx; bx.w = yy + hy;
    reinterpret_cast<float4*>(boxes)[i] = bx;

    float lg[NCLS] = {v1.x, v1.y, v1.z, v1.w, v2.x, v2.y, v2.z, v2.w,
                      v3.x, v3.y, v3.z, v3.w, v4.x, v4.y, v4.z, v4.w};
    float best = -1.0f; int bi = 0;
    #pragma unroll
    for (int c = 0; c < NCLS; ++c) {
      float s = 1.0f / (1.0f + expf(-lg[c]));
      if (s > best) { best = s; bi = c; }
    }
    score[i] = best;
    v = (best >= CONF_T) ? bi : -1;
    cls[i] = v;
  }

  int lane = t & 63;
  #pragma unroll
  for (int c = 0; c < NCLS; ++c) {
    unsigned long long bl = __ballot(v == c);
    if (lane == 0 && bl) atomicAdd(&hist[c], __popcll(bl));
  }
  __syncthreads();
  if (t < NCLS) counts[(b * NCLS + t) * nchunk + chunk] = hist[t];
}

// ---------------- K2: per-(b,c) exclusive scan over chunk counts ----------------
__global__ __launch_bounds__(256) void k_scan(
    const int* __restrict__ counts, int* __restrict__ offs, int* __restrict__ ktot,
    int nchunk)
{
  const int bc = blockIdx.x;
  const int t = threadIdx.x;
  __shared__ int c_[256];
  __shared__ int o_[257];
  if (t < nchunk) c_[t] = counts[bc * nchunk + t];
  __syncthreads();
  if (t == 0) {
    int run = 0;
    for (int i = 0; i < nchunk; ++i) { o_[i] = run; run += c_[i]; }
    o_[nchunk] = run;
  }
  __syncthreads();
  if (t < nchunk) offs[bc * nchunk + t] = o_[t];
  if (t == 0) ktot[bc] = o_[nchunk];
}

// ---------------- K3: stable parallel scatter into per-(b,c) candidate lists ----------------
__global__ __launch_bounds__(256) void k_scatter(
    const float* __restrict__ score, const int* __restrict__ cls,
    const float* __restrict__ boxes, const int* __restrict__ offs,
    float* __restrict__ cand_sc, float* __restrict__ cand_bx,
    int N, int nchunk)
{
  const int b = blockIdx.x / nchunk;
  const int chunk = blockIdx.x % nchunk;
  const int t = threadIdx.x;
  const int n = chunk * 256 + t;

  __shared__ int wcnt[4][NCLS];
  int v = (n < N) ? cls[(size_t)b * N + n] : -1;
  int lane = t & 63, w = t >> 6;
  int myrank = 0;
  #pragma unroll
  for (int c = 0; c < NCLS; ++c) {
    unsigned long long bl = __ballot(v == c);
    if (lane == 0) wcnt[w][c] = __popcll(bl);
    if (v == c) myrank = __popcll(bl & ((1ull << lane) - 1ull));
  }
  __syncthreads();
  if (v >= 0) {
    int pre = 0;
    #pragma unroll
    for (int i = 0; i < 4; ++i) if (i < w) pre += wcnt[i][v];
    int pos = offs[(b * NCLS + v) * nchunk + chunk] + pre + myrank;
    if (pos < CAP) {
      int bc = b * NCLS + v;
      cand_sc[(size_t)bc * CAP + pos] = score[(size_t)b * N + n];
      reinterpret_cast<float4*>(cand_bx)[(size_t)bc * CAP + pos] =
          reinterpret_cast<const float4*>(boxes)[(size_t)b * N + n];
    }
  }
}

// ---------------- K4: per-(b,c) soft-NMS, 1024 threads, LDS-light reduction ----------------
__global__ __launch_bounds__(1024) void k_nms(
    const float* __restrict__ cand_sc, const float* __restrict__ cand_bx,
    const int* __restrict__ ktot,
    float* __restrict__ out_box, float* __restrict__ out_sc, int* __restrict__ out_pick)
{
  #pragma clang fp contract(off)
  const int bc = blockIdx.x;
  const int t = threadIdx.x;

  __shared__ float4 s_box[CAP];                 // 64 KB: all candidate boxes
  __shared__ unsigned long long s_pair[1024];   // 8 KB: per-thread local-max keys
  __shared__ unsigned long long s_final;

  int K = ktot[bc]; if (K > CAP) K = CAP;

  float  rsc[4];
  float4 rbx[4];
  #pragma unroll
  for (int k = 0; k < 4; ++k) {
    int j = k * 1024 + t;
    if (j < K) {
      rsc[k] = cand_sc[(size_t)bc * CAP + j];
      float4 bb = reinterpret_cast<const float4*>(cand_bx)[(size_t)bc * CAP + j];
      rbx[k] = bb;
      s_box[j] = bb;
    } else {
      rsc[k] = NEGF;
      rbx[k].x = rbx[k].y = rbx[k].z = rbx[k].w = 0.0f;
    }
  }

  float* ob  = out_box  + (size_t)bc * TDET * 4;
  float* osc = out_sc   + (size_t)bc * TDET;
  int*   opk = out_pick + (size_t)bc * TDET;

  int iter = 0;
  for (; iter < TDET; ++iter) {
    // thread-local argmax over 4 slots (strict > => lowest slot k => lowest j)
    float bs = rsc[0]; int bk = 0;
    #pragma unroll
    for (int k = 1; k < 4; ++k)
      if (rsc[k] > bs) { bs = rsc[k]; bk = k; }
    s_pair[t] = packkey(bs, bk * 1024 + t);
    __syncthreads();                       // A: all keys visible (also orders s_box init)

    if (t < 64) {                          // wave 0 reduces 1024 -> 1
      unsigned long long m = s_pair[t];
      #pragma unroll
      for (int i = 1; i < 16; ++i) {
        unsigned long long o = s_pair[i * 64 + t];   // lanes contiguous: conflict-free
        if (o > m) m = o;
      }
      #pragma unroll
      for (int d = 1; d < 64; d <<= 1) {
        unsigned long long o = __shfl_xor(m, d);
        if (o > m) m = o;
      }
      if (t == 0) s_final = m;
    }
    __syncthreads();                       // B: final key visible

    unsigned long long bkey = s_final;
    float bestS = unpack_score(bkey);
    if (bestS < CONF_T) break;             // uniform: no further picks possible
    int bestJ = (int)(~(unsigned int)bkey);

    float4 sb = s_box[bestJ];              // broadcast read (same addr all lanes)
    if (t == 0) {
      ob[iter * 4 + 0] = sb.x; ob[iter * 4 + 1] = sb.y;
      ob[iter * 4 + 2] = sb.z; ob[iter * 4 + 3] = sb.w;
      osc[iter] = bestS; opk[iter] = 1;
    }
    float areaS = (sb.z - sb.x) * (sb.w - sb.y);
    #pragma unroll
    for (int k = 0; k < 4; ++k) {
      int j = k * 1024 + t;
      if (j >= K) continue;
      if (rsc[k] == NEGF) continue;        // dead: can never be picked again
      if (j == bestJ) { rsc[k] = NEGF; continue; }
      float ltx = fmaxf(sb.x, rbx[k].x);
      float lty = fmaxf(sb.y, rbx[k].y);
      float rbv = fminf(sb.z, rbx[k].z);
      float rby = fminf(sb.w, rbx[k].w);
      float wx = fmaxf(rbv - ltx, 0.0f);
      float wy = fmaxf(rby - lty, 0.0f);
      float inter = wx * wy;
      float areaB = (rbx[k].z - rbx[k].x) * (rbx[k].w - rbx[k].y);
      float uni = (areaS + areaB) - inter;
      float iou = (uni > 0.0f) ? (inter / uni) : 0.0f;
      float ns;
      if (iou > 0.5f) ns = NEGF;
      else {
        ns = rsc[k] * expf((-10.0f * iou) * iou);
        if (ns < CONF_T) ns = NEGF;        // pruning: output-equivalent
      }
      rsc[k] = ns;
    }
    // no barrier here: next iter's s_pair writes are ordered by barrier A,
    // and s_pair reads (wave0, iter i) completed before barrier B(i).
  }
  for (int r = iter + t; r < TDET; r += 1024) opk[r] = 0;
}

// ---------------- K5: per-batch compaction + stable top-100 (bitonic) ----------------
__global__ __launch_bounds__(1024) void k_post(
    const float* __restrict__ out_box, const float* __restrict__ out_sc,
    const int* __restrict__ out_pick,
    float* __restrict__ out, int B)
{
  #pragma clang fp contract(off)
  const int b = blockIdx.x;
  const int t = threadIdx.x;

  __shared__ float p_sc[MTOT];
  __shared__ float p_bx[MTOT * 4];
  __shared__ unsigned char p_v[MTOT];
  __shared__ float q_sc[MTOT];
  __shared__ short q_m[MTOT];
  __shared__ int s_wtot[16];
  __shared__ unsigned long long s_key[2048];

  // load class-major entries (m = c*100 + step)
  for (int m = t; m < MTOT; m += 1024) {
    int c = m / TDET, tt = m % TDET;
    int lanebc = b * NCLS + c;
    int pk = out_pick[(size_t)lanebc * TDET + tt];
    p_v[m] = (unsigned char)pk;
    if (pk) {
      p_sc[m] = out_sc[(size_t)lanebc * TDET + tt];
      p_bx[m * 4 + 0] = out_box[((size_t)lanebc * TDET + tt) * 4 + 0];
      p_bx[m * 4 + 1] = out_box[((size_t)lanebc * TDET + tt) * 4 + 1];
      p_bx[m * 4 + 2] = out_box[((size_t)lanebc * TDET + tt) * 4 + 2];
      p_bx[m * 4 + 3] = out_box[((size_t)lanebc * TDET + tt) * 4 + 3];
    } else {
      p_sc[m] = 0.0f;
      p_bx[m * 4 + 0] = 0.0f; p_bx[m * 4 + 1] = 0.0f;
      p_bx[m * 4 + 2] = 0.0f; p_bx[m * 4 + 3] = 0.0f;
    }
  }
  __syncthreads();

  // stable compaction (class-major order preserved)
  int running = 0;
  for (int base = 0; base < MTOT; base += 1024) {
    int m = base + t;
    bool v = (m < MTOT) && p_v[m];
    unsigned long long ball = __ballot(v);
    int lane = t & 63, w = t >> 6;
    if (lane == 0) s_wtot[w] = __popcll(ball);
    __syncthreads();
    int off = 0, tot = 0;
    #pragma unroll
    for (int i = 0; i < 16; ++i) {
      int ci = s_wtot[i];
      if (i < w) off += ci;
      tot += ci;
    }
    if (v) {
      int wpre = __popcll(ball & ((1ull << lane) - 1ull));
      int j = running + off + wpre;
      q_sc[j] = p_sc[m];
      q_m[j] = (short)m;
    }
    running += tot;
    __syncthreads();
  }
  int nv = running;
  bool over = nv > TDET;

  if (over) {
    // keys: inverted so ascending bitonic == (score desc, position asc)
    for (int e = t; e < 2048; e += 1024) {
      unsigned long long kk = 0;
      if (e < nv) {
        unsigned int sb = __float_as_uint(q_sc[e]);   // valid scores > 0
        kk = ((unsigned long long)sb << 32) | (unsigned int)(~e);
      }
      s_key[e] = ~kk;
    }
    for (int kk2 = 2; kk2 <= 2048; kk2 <<= 1) {
      for (int j = kk2 >> 1; j > 0; j >>= 1) {
        __syncthreads();
        int e = ((t & ~(j - 1)) << 1) | (t & (j - 1));
        int q = e | j;
        unsigned long long a = s_key[e], bb = s_key[q];
        bool up = ((e & kk2) == 0);
        bool sw = up ? (a > bb) : (a < bb);
        if (sw) { s_key[e] = bb; s_key[q] = a; }
      }
    }
    __syncthreads();
  }

  // write: [B] valid, [B,100,4] boxes, [B,100] scores, [B,100] classes (all f32)
  int vd = nv < TDET ? nv : TDET;
  int base_box = B;
  int base_sc  = B + B * TDET * 4;
  int base_cl  = base_sc + B * TDET;
  if (t == 0) out[b] = (float)vd;
  if (t < TDET) {
    float sc = 0.0f, cl = -1.0f, b0 = 0.0f, b1 = 0.0f, b2 = 0.0f, b3 = 0.0f;
    int p = -1;
    if (t < nv) p = over ? (int)(unsigned int)s_key[t] : t;
    if (p >= 0) {
      int m = q_m[p];
      sc = q_sc[p];
      cl = (float)(m / TDET);
      b0 = p_bx[m * 4 + 0]; b1 = p_bx[m * 4 + 1];
      b2 = p_bx[m * 4 + 2]; b3 = p_bx[m * 4 + 3];
    }
    int o = b * TDET + t;
    out[base_box + o * 4 + 0] = b0;
    out[base_box + o * 4 + 1] = b1;
    out[base_box + o * 4 + 2] = b2;
    out[base_box + o * 4 + 3] = b3;
    out[base_sc + o] = sc;
    out[base_cl + o] = cl;
  }
}

extern "C" void kernel_launch(void* const* d_in, const int* in_sizes, int n_in,
                              void* d_out, int out_size, void* d_ws, size_t ws_size,
                              hipStream_t stream) {
  const float* pred = (const float*)d_in[0];
  const float* anch = (const float*)d_in[1];
  int N  = in_sizes[1] / 4;       // 49104
  int BN = in_sizes[0] / 20;      // B*N
  int B  = BN / N;                // 4
  int nchunk = (N + 255) / 256;   // 192
  int NBC = B * NCLS;             // 64

  char* ws = (char*)d_ws;
  size_t off = 0;
  float* boxes  = (float*)(ws + off); off += (size_t)BN * 4 * sizeof(float);
  float* candbx = (float*)(ws + off); off += (size_t)NBC * CAP * 4 * sizeof(float);
  float* obox   = (float*)(ws + off); off += (size_t)NBC * TDET * 4 * sizeof(float);
  float* score  = (float*)(ws + off); off += (size_t)BN * sizeof(float);
  float* candsc = (float*)(ws + off); off += (size_t)NBC * CAP * sizeof(float);
  float* osc    = (float*)(ws + off); off += (size_t)NBC * TDET * sizeof(float);
  int*   cls    = (int*)(ws + off);   off += (size_t)BN * sizeof(int);
  int*   counts = (int*)(ws + off);   off += (size_t)NBC * nchunk * sizeof(int);
  int*   offs   = (int*)(ws + off);   off += (size_t)NBC * nchunk * sizeof(int);
  int*   ktot   = (int*)(ws + off);   off += (size_t)NBC * sizeof(int);
  int*   opick  = (int*)(ws + off);   off += (size_t)NBC * TDET * sizeof(int);

  k_decode<<<B * nchunk, 256, 0, stream>>>(pred, anch, boxes, score, cls, counts, N, nchunk);
  k_scan<<<NBC, 256, 0, stream>>>(counts, offs, ktot, nchunk);
  k_scatter<<<B * nchunk, 256, 0, stream>>>(score, cls, boxes, offs, candsc, candbx, N, nchunk);
  k_nms<<<NBC, 1024, 0, stream>>>(candsc, candbx, ktot, obox, osc, opick);
  k_post<<<B, 1024, 0, stream>>>(obox, osc, opick, (float*)d_out, B);
}